// Round 2
// baseline (394.586 us; speedup 1.0000x reference)
//
#include <hip/hip_runtime.h>
#include <cstdint>

#define DEV static __device__ __forceinline__

typedef unsigned short u16;
typedef __attribute__((ext_vector_type(8))) _Float16 half8;
typedef __attribute__((ext_vector_type(4))) float f32x4;
typedef __attribute__((ext_vector_type(4))) unsigned short u16x4;

DEV u16 f2h_bits(float f) {
  _Float16 h = (_Float16)f;
  union { _Float16 h; u16 u; } cv; cv.h = h; return cv.u;
}

DEV void async_cp16(const void* g, void* l) {
  __builtin_amdgcn_global_load_lds(
      (const __attribute__((address_space(1))) void*)g,
      (__attribute__((address_space(3))) void*)l, 16, 0, 0);
}

// ---------------- fp32 -> fp16 convert (vectorized) ----------------
__global__ void cvt_f16(const float4* __restrict__ in, u16* __restrict__ out) {
  const int i = blockIdx.x * 256 + threadIdx.x;   // indexes float4
  float4 f = in[i];
  u16x4 u;
  u.x = f2h_bits(f.x); u.y = f2h_bits(f.y); u.z = f2h_bits(f.z); u.w = f2h_bits(f.w);
  *(u16x4*)(out + i * 4) = u;
}

// ---------------- W [K][N] fp32 -> Wt [N][K] fp16 ----------------
__global__ void transpose_cvt(const float* __restrict__ Wf, u16* __restrict__ Wt) {
  __shared__ float tile[32][33];
  const int bx = blockIdx.x & 31, by = blockIdx.x >> 5;
  const int tx = threadIdx.x & 31, ty = threadIdx.x >> 5;  // ty 0..7
#pragma unroll
  for (int r = 0; r < 32; r += 8)
    tile[ty + r][tx] = Wf[(by * 32 + ty + r) * 1024 + bx * 32 + tx];
  __syncthreads();
#pragma unroll
  for (int r = 0; r < 32; r += 8)
    Wt[(bx * 32 + ty + r) * 1024 + by * 32 + tx] = f2h_bits(tile[tx][ty + r]);
}

// ---------------- GEMM: C[M=8192,N=1024] = A[M,1024] * Bt[N,1024]^T + bias ----------------
// MODE 0: qh [B,H,T,64] fp16, *0.125   MODE 1: kh [B,H,T,64] fp16
// MODE 2: vt [B,H,64,T] fp16           MODE 3: fp32 row-major out
template<int MODE>
__launch_bounds__(256, 2)
__global__ void gemm_kernel(const u16* __restrict__ A, const u16* __restrict__ Bt,
                            const float* __restrict__ bias, void* __restrict__ out)
{
  __shared__ u16 As[128 * 32];
  __shared__ u16 Bs[128 * 32];
  const int tid = threadIdx.x;
  const int wave = tid >> 6, lane = tid & 63;
  const int l15 = lane & 15, lg = lane >> 4;
  const int bm = blockIdx.x >> 3, bn = blockIdx.x & 7;
  const int m0 = bm * 128, n0 = bn * 128;
  const int wr = wave >> 1, wc = wave & 1;

  const f32x4 fz = {0.f, 0.f, 0.f, 0.f};
  f32x4 acc[4][4];
#pragma unroll
  for (int m = 0; m < 4; ++m)
#pragma unroll
    for (int n = 0; n < 4; ++n) acc[m][n] = fz;

  const int ar = tid >> 2, ac = (tid & 3) << 3;
  const u16* gA0 = A + (m0 + ar) * 1024 + ac;
  const u16* gA1 = A + (m0 + 64 + ar) * 1024 + ac;
  const u16* gB0 = Bt + (n0 + ar) * 1024 + ac;
  const u16* gB1 = Bt + (n0 + 64 + ar) * 1024 + ac;
  u16* lA0 = As + wave * 512;
  u16* lA1 = As + 2048 + wave * 512;
  u16* lB0 = Bs + wave * 512;
  u16* lB1 = Bs + 2048 + wave * 512;

  for (int kt = 0; kt < 1024; kt += 32) {
    __syncthreads();
    async_cp16(gA0 + kt, lA0);
    async_cp16(gA1 + kt, lA1);
    async_cp16(gB0 + kt, lB0);
    async_cp16(gB1 + kt, lB1);
    __syncthreads();
    half8 af[4], bfr[4];
#pragma unroll
    for (int m = 0; m < 4; ++m)
      af[m] = *(const half8*)(As + (wr * 64 + m * 16 + l15) * 32 + lg * 8);
#pragma unroll
    for (int n = 0; n < 4; ++n)
      bfr[n] = *(const half8*)(Bs + (wc * 64 + n * 16 + l15) * 32 + lg * 8);
#pragma unroll
    for (int m = 0; m < 4; ++m)
#pragma unroll
      for (int n = 0; n < 4; ++n)
        acc[m][n] = __builtin_amdgcn_mfma_f32_16x16x32_f16(af[m], bfr[n], acc[m][n], 0, 0, 0);
  }

#pragma unroll
  for (int m = 0; m < 4; ++m) {
    const int Rb = m0 + wr * 64 + m * 16 + lg * 4;
#pragma unroll
    for (int n = 0; n < 4; ++n) {
      const int C = n0 + wc * 64 + n * 16 + l15;
      const float bv = bias[C];
#pragma unroll
      for (int i = 0; i < 4; ++i) {
        const int R = Rb + i;
        const float vv = acc[m][n][i] + bv;
        if (MODE == 0) {
          const int b = R >> 11, t = R & 2047, hh = C >> 6, d = C & 63;
          ((u16*)out)[((b * 16 + hh) * 2048 + t) * 64 + d] = f2h_bits(vv * 0.125f);
        } else if (MODE == 1) {
          const int b = R >> 11, t = R & 2047, hh = C >> 6, d = C & 63;
          ((u16*)out)[((b * 16 + hh) * 2048 + t) * 64 + d] = f2h_bits(vv);
        } else if (MODE == 2) {
          const int b = R >> 11, t = R & 2047, hh = C >> 6, d = C & 63;
          ((u16*)out)[((b * 16 + hh) * 64 + d) * 2048 + t] = f2h_bits(vv);
        } else {
          ((float*)out)[R * 1024 + C] = vv;
        }
      }
    }
  }
}

// ---------------- flash attention ----------------
// qh,kh: [B,H,T,64] fp16 (qh pre-scaled by 0.125); vt: [B,H,64,T] fp16
// O: [B,T,H*64] fp16. Block: 64 Q-rows, 4 waves x 16 rows, KVBLK=64.
__launch_bounds__(256, 2)
__global__ void attn_kernel(const u16* __restrict__ qh, const u16* __restrict__ kh,
                            const u16* __restrict__ vt, u16* __restrict__ O)
{
  __shared__ u16 Qs[4096], Ks[4096], Vs[4096];
  __shared__ u16 Ps[4][1024];
  const int tid = threadIdx.x, wave = tid >> 6, lane = tid & 63;
  const int l15 = lane & 15, lg = lane >> 4;
  const int bh = blockIdx.x >> 5;          // b*16+h
  const int q0 = (blockIdx.x & 31) << 6;
  const int b = bh >> 4, h = bh & 15;

  const char* qbase = (const char*)(qh + (bh * 2048 + q0) * 64);
  const char* kbase = (const char*)(kh + bh * 2048 * 64);
  const char* vbase = (const char*)(vt + bh * 64 * 2048);

  // stage Q (swizzled content via pre-swizzled source; LDS dest linear)
#pragma unroll
  for (int c = 0; c < 2; ++c) {
    const int x = c * 4096 + tid * 16;
    const int row = x >> 7;
    async_cp16(qbase + (x ^ ((row & 7) << 4)), (char*)Qs + c * 4096 + wave * 1024);
  }
  __syncthreads();

  half8 aq[2];
  {
    const int qr = wave * 16 + l15;
#pragma unroll
    for (int hh = 0; hh < 2; ++hh) {
      const int addr = (qr * 128 + hh * 64 + lg * 16) ^ ((qr & 7) << 4);
      aq[hh] = *(const half8*)((const char*)Qs + addr);
    }
  }

  const f32x4 fz = {0.f, 0.f, 0.f, 0.f};
  f32x4 o[4];
  float mI[4], lI[4];
#pragma unroll
  for (int i = 0; i < 4; ++i) { o[i] = fz; mI[i] = -3.0e38f; lI[i] = 0.f; }

  for (int kv = 0; kv < 2048; kv += 64) {
    __syncthreads();
#pragma unroll
    for (int c = 0; c < 2; ++c) {
      const int x = c * 4096 + tid * 16;
      const int row = x >> 7;
      const int sw = ((row & 7) << 4);
      async_cp16(kbase + (size_t)kv * 128 + (x ^ sw), (char*)Ks + c * 4096 + wave * 1024);
      async_cp16(vbase + (size_t)row * 4096 + kv * 2 + ((x & 127) ^ sw),
                 (char*)Vs + c * 4096 + wave * 1024);
    }
    __syncthreads();

    // S = Q K^T (scale already folded into qh)
    f32x4 s[4];
#pragma unroll
    for (int n = 0; n < 4; ++n) s[n] = fz;
#pragma unroll
    for (int n = 0; n < 4; ++n) {
      const int krow = n * 16 + l15;
#pragma unroll
      for (int hh = 0; hh < 2; ++hh) {
        const int addr = (krow * 128 + hh * 64 + lg * 16) ^ ((krow & 7) << 4);
        half8 bk = *(const half8*)((const char*)Ks + addr);
        s[n] = __builtin_amdgcn_mfma_f32_16x16x32_f16(aq[hh], bk, s[n], 0, 0, 0);
      }
    }

    // online softmax; lane's rows are lg*4+i
    float p[4][4];
#pragma unroll
    for (int i = 0; i < 4; ++i) {
      float mx = fmaxf(fmaxf(s[0][i], s[1][i]), fmaxf(s[2][i], s[3][i]));
      mx = fmaxf(mx, __shfl_xor(mx, 1, 16));
      mx = fmaxf(mx, __shfl_xor(mx, 2, 16));
      mx = fmaxf(mx, __shfl_xor(mx, 4, 16));
      mx = fmaxf(mx, __shfl_xor(mx, 8, 16));
      const float mn = fmaxf(mI[i], mx);
      const float corr = exp2f((mI[i] - mn) * 1.44269504f);
      float rs = 0.f;
#pragma unroll
      for (int n = 0; n < 4; ++n) {
        const float pv = exp2f((s[n][i] - mn) * 1.44269504f);
        p[n][i] = pv; rs += pv;
      }
      rs += __shfl_xor(rs, 1, 16);
      rs += __shfl_xor(rs, 2, 16);
      rs += __shfl_xor(rs, 4, 16);
      rs += __shfl_xor(rs, 8, 16);
      lI[i] = lI[i] * corr + rs;
      mI[i] = mn;
#pragma unroll
      for (int d = 0; d < 4; ++d) o[d][i] *= corr;
    }

    // P -> per-wave LDS (swizzled), reread as A-fragments
    char* pw = (char*)&Ps[wave][0];
#pragma unroll
    for (int n = 0; n < 4; ++n)
#pragma unroll
      for (int i = 0; i < 4; ++i) {
        const int pr = lg * 4 + i;
        const int addr = (pr * 128 + (n * 16 + l15) * 2) ^ ((pr & 7) << 4);
        *(u16*)(pw + addr) = f2h_bits(p[n][i]);
      }
    half8 pa[2];
#pragma unroll
    for (int hh = 0; hh < 2; ++hh) {
      const int addr = (l15 * 128 + hh * 64 + lg * 16) ^ ((l15 & 7) << 4);
      pa[hh] = *(const half8*)(pw + addr);
    }

    // O += P V   (B-frag from Vt rows: contiguous)
#pragma unroll
    for (int nd = 0; nd < 4; ++nd) {
      const int dr = nd * 16 + l15;
#pragma unroll
      for (int hh = 0; hh < 2; ++hh) {
        const int addr = (dr * 128 + hh * 64 + lg * 16) ^ ((dr & 7) << 4);
        half8 bv = *(const half8*)((const char*)Vs + addr);
        o[nd] = __builtin_amdgcn_mfma_f32_16x16x32_f16(pa[hh], bv, o[nd], 0, 0, 0);
      }
    }
  }

#pragma unroll
  for (int i = 0; i < 4; ++i) {
    const float inv = 1.f / lI[i];
    const int t = q0 + wave * 16 + lg * 4 + i;
    u16* orow = O + ((size_t)(b * 2048 + t)) * 1024 + h * 64;
#pragma unroll
    for (int nd = 0; nd < 4; ++nd)
      orow[nd * 16 + l15] = f2h_bits(o[nd][i] * inv);
  }
}

extern "C" void kernel_launch(void* const* d_in, const int* in_sizes, int n_in,
                              void* d_out, int out_size, void* d_ws, size_t ws_size,
                              hipStream_t stream)
{
  const float* q  = (const float*)d_in[0];
  const float* k  = (const float*)d_in[1];
  const float* v  = (const float*)d_in[2];
  const float* Wq = (const float*)d_in[3];
  const float* bq = (const float*)d_in[4];
  const float* Wk = (const float*)d_in[5];
  const float* bk = (const float*)d_in[6];
  const float* Wv = (const float*)d_in[7];
  const float* bv = (const float*)d_in[8];
  const float* Wo = (const float*)d_in[9];
  const float* bo = (const float*)d_in[10];

  u16* W = (u16*)d_ws;
  const unsigned MB = 1u << 20;           // element (u16) units
  u16* wtq = W + 0 * MB;
  u16* wtk = W + 1 * MB;
  u16* wtv = W + 2 * MB;
  u16* wto = W + 3 * MB;
  u16* qhb = W + 4 * MB;                  // 8M elems
  u16* khb = W + 12 * MB;
  u16* vtb = W + 20 * MB;
  u16* Xb  = W + 28 * MB;                 // input cvt buffer / attention output

  transpose_cvt<<<1024, 256, 0, stream>>>(Wq, wtq);
  transpose_cvt<<<1024, 256, 0, stream>>>(Wk, wtk);
  transpose_cvt<<<1024, 256, 0, stream>>>(Wv, wtv);
  transpose_cvt<<<1024, 256, 0, stream>>>(Wo, wto);

  cvt_f16<<<8192, 256, 0, stream>>>((const float4*)q, Xb);
  gemm_kernel<0><<<512, 256, 0, stream>>>(Xb, wtq, bq, qhb);
  cvt_f16<<<8192, 256, 0, stream>>>((const float4*)k, Xb);
  gemm_kernel<1><<<512, 256, 0, stream>>>(Xb, wtk, bk, khb);
  cvt_f16<<<8192, 256, 0, stream>>>((const float4*)v, Xb);
  gemm_kernel<2><<<512, 256, 0, stream>>>(Xb, wtv, bv, vtb);

  attn_kernel<<<2048, 256, 0, stream>>>(qhb, khb, vtb, Xb);
  gemm_kernel<3><<<512, 256, 0, stream>>>(Xb, wto, bo, (float*)d_out);
}

// Round 5
// 309.579 us; speedup vs baseline: 1.2746x; 1.2746x over previous
//
#include <hip/hip_runtime.h>
#include <cstdint>

#define DEV static __device__ __forceinline__

typedef unsigned short u16;
typedef unsigned int u32;
typedef __attribute__((ext_vector_type(8))) _Float16 half8;
typedef __attribute__((ext_vector_type(4))) float f32x4;
typedef __attribute__((ext_vector_type(4))) unsigned short u16x4;

DEV u16 f2h_bits(float f) {
  _Float16 h = (_Float16)f;
  union { _Float16 h; u16 u; } cv; cv.h = h; return cv.u;
}

DEV u32 pack2h(float a, float b) {
  union { __fp16 __attribute__((ext_vector_type(2))) h; u32 u; } cv;
  cv.h = __builtin_amdgcn_cvt_pkrtz(a, b);
  return cv.u;
}

DEV void async_cp16(const void* g, void* l) {
  __builtin_amdgcn_global_load_lds(
      (const __attribute__((address_space(1))) void*)g,
      (__attribute__((address_space(3))) void*)l, 16, 0, 0);
}

// ---------------- fp32 -> fp16 convert (vectorized) ----------------
__global__ void cvt_f16(const float4* __restrict__ in, u16* __restrict__ out) {
  const int i = blockIdx.x * 256 + threadIdx.x;   // indexes float4
  float4 f = in[i];
  u16x4 u;
  u.x = f2h_bits(f.x); u.y = f2h_bits(f.y); u.z = f2h_bits(f.z); u.w = f2h_bits(f.w);
  *(u16x4*)(out + i * 4) = u;
}

// ---------------- W [K][N] fp32 -> Wt [N][K] fp16 ----------------
__global__ void transpose_cvt(const float* __restrict__ Wf, u16* __restrict__ Wt) {
  __shared__ float tile[32][33];
  const int bx = blockIdx.x & 31, by = blockIdx.x >> 5;
  const int tx = threadIdx.x & 31, ty = threadIdx.x >> 5;  // ty 0..7
#pragma unroll
  for (int r = 0; r < 32; r += 8)
    tile[ty + r][tx] = Wf[(by * 32 + ty + r) * 1024 + bx * 32 + tx];
  __syncthreads();
#pragma unroll
  for (int r = 0; r < 32; r += 8)
    Wt[(bx * 32 + ty + r) * 1024 + by * 32 + tx] = f2h_bits(tile[tx][ty + r]);
}

// ---------------- GEMM: C[M=8192,N=1024] = A[M,1024] * Bt[N,1024]^T + bias ----------------
// MODE 0: qh [B,H,T,64] fp16, *0.125*log2e   MODE 1: kh [B,H,T,64] fp16
// MODE 2: vt [B,H,64,T] fp16                 MODE 3: fp32 row-major out
// 2-phase double-buffered staging (T3-minimum).
template<int MODE>
__launch_bounds__(256, 2)
__global__ void gemm_kernel(const u16* __restrict__ A, const u16* __restrict__ Bt,
                            const float* __restrict__ bias, void* __restrict__ out)
{
  __shared__ u16 As[2][4096];
  __shared__ u16 Bs[2][4096];
  const int tid = threadIdx.x;
  const int wave = tid >> 6, lane = tid & 63;
  const int l15 = lane & 15, lg = lane >> 4;
  const int bm = blockIdx.x >> 3, bn = blockIdx.x & 7;
  const int m0 = bm * 128, n0 = bn * 128;
  const int wr = wave >> 1, wc = wave & 1;

  const f32x4 fz = {0.f, 0.f, 0.f, 0.f};
  f32x4 acc[4][4];
#pragma unroll
  for (int m = 0; m < 4; ++m)
#pragma unroll
    for (int n = 0; n < 4; ++n) acc[m][n] = fz;

  const int ar = tid >> 2, ac = (tid & 3) << 3;
  const u16* gA0 = A + (m0 + ar) * 1024 + ac;
  const u16* gA1 = A + (m0 + 64 + ar) * 1024 + ac;
  const u16* gB0 = Bt + (n0 + ar) * 1024 + ac;
  const u16* gB1 = Bt + (n0 + 64 + ar) * 1024 + ac;

  // each wave stages 64 lanes x 16B = 512 elements -> wave spacing 512 elems
#define STAGE_G(buf, kt)                                   \
  do {                                                     \
    async_cp16(gA0 + (kt), (u16*)As[buf] + wave * 512);    \
    async_cp16(gA1 + (kt), (u16*)As[buf] + 2048 + wave * 512); \
    async_cp16(gB0 + (kt), (u16*)Bs[buf] + wave * 512);    \
    async_cp16(gB1 + (kt), (u16*)Bs[buf] + 2048 + wave * 512); \
  } while (0)

  STAGE_G(0, 0);
  __syncthreads();

  for (int t = 0; t < 32; ++t) {
    const int cb = t & 1;
    if (t < 31) STAGE_G(cb ^ 1, (t + 1) * 32);
    const u16* Ab = As[cb];
    const u16* Bb = Bs[cb];
    half8 af[4], bfr[4];
#pragma unroll
    for (int m = 0; m < 4; ++m)
      af[m] = *(const half8*)(Ab + (wr * 64 + m * 16 + l15) * 32 + lg * 8);
#pragma unroll
    for (int n = 0; n < 4; ++n)
      bfr[n] = *(const half8*)(Bb + (wc * 64 + n * 16 + l15) * 32 + lg * 8);
#pragma unroll
    for (int m = 0; m < 4; ++m)
#pragma unroll
      for (int n = 0; n < 4; ++n)
        acc[m][n] = __builtin_amdgcn_mfma_f32_16x16x32_f16(af[m], bfr[n], acc[m][n], 0, 0, 0);
    __syncthreads();
  }
#undef STAGE_G

#pragma unroll
  for (int m = 0; m < 4; ++m) {
    const int Rb = m0 + wr * 64 + m * 16 + lg * 4;
#pragma unroll
    for (int n = 0; n < 4; ++n) {
      const int C = n0 + wc * 64 + n * 16 + l15;
      const float bv = bias[C];
#pragma unroll
      for (int i = 0; i < 4; ++i) {
        const int R = Rb + i;
        const float vv = acc[m][n][i] + bv;
        if (MODE == 0) {
          const int b = R >> 11, t = R & 2047, hh = C >> 6, d = C & 63;
          // fold softmax scale AND log2e so attention works in exp2 domain
          ((u16*)out)[((b * 16 + hh) * 2048 + t) * 64 + d] = f2h_bits(vv * 0.18033688f);
        } else if (MODE == 1) {
          const int b = R >> 11, t = R & 2047, hh = C >> 6, d = C & 63;
          ((u16*)out)[((b * 16 + hh) * 2048 + t) * 64 + d] = f2h_bits(vv);
        } else if (MODE == 2) {
          const int b = R >> 11, t = R & 2047, hh = C >> 6, d = C & 63;
          ((u16*)out)[((b * 16 + hh) * 64 + d) * 2048 + t] = f2h_bits(vv);
        } else {
          ((float*)out)[R * 1024 + C] = vv;
        }
      }
    }
  }
}

// ---------------- flash attention (swapped QK^T, in-lane softmax) ----------------
// qh,kh: [B,H,T,64] fp16 (qh pre-scaled by 0.125*log2e); vt: [B,H,64,T] fp16
// O: [B,T,H*64] fp16. Block: 64 Q-rows, 4 waves x 16 rows, KVBLK=64.
// S^T = mfma(K,Q): lane (l15,lg) holds S[q=l15][kv=n*16+lg*4+i] -> softmax in-lane.
__launch_bounds__(256, 2)
__global__ void attn_kernel(const u16* __restrict__ qh, const u16* __restrict__ kh,
                            const u16* __restrict__ vt, u16* __restrict__ O)
{
  __shared__ u16 KV[2][2][4096];   // [buf][K/V][64 rows x 64 cols]
  __shared__ u16 QP[4096];         // Q staging, then per-wave P (wave*2048 bytes)
  const int tid = threadIdx.x, wave = tid >> 6, lane = tid & 63;
  const int l15 = lane & 15, lg = lane >> 4;
  const int bh = blockIdx.x >> 5;          // b*16+h
  const int q0 = (blockIdx.x & 31) << 6;
  const int b = bh >> 4, h = bh & 15;

  const char* qbase = (const char*)(qh + (size_t)(bh * 2048 + q0) * 64);
  const char* kbase = (const char*)(kh + (size_t)bh * 2048 * 64);
  const char* vbase = (const char*)(vt + (size_t)bh * 64 * 2048);

  // per-lane staging source offsets (content-swizzle via pre-swizzled source)
  const int x0 = tid * 16, x1 = 4096 + tid * 16;
  const int r0 = x0 >> 7, r1 = x1 >> 7;
  const char* ks0 = kbase + (x0 ^ ((r0 & 7) << 4));
  const char* ks1 = kbase + (x1 ^ ((r1 & 7) << 4));
  const char* vs0 = vbase + (size_t)r0 * 4096 + ((x0 & 127) ^ ((r0 & 7) << 4));
  const char* vs1 = vbase + (size_t)r1 * 4096 + ((x1 & 127) ^ ((r1 & 7) << 4));

#define STAGE_KV(buf, t)                                                      \
  do {                                                                        \
    async_cp16(ks0 + (size_t)(t) * 8192, (char*)KV[buf][0] + wave * 1024);    \
    async_cp16(ks1 + (size_t)(t) * 8192, (char*)KV[buf][0] + 4096 + wave * 1024); \
    async_cp16(vs0 + (size_t)(t) * 128, (char*)KV[buf][1] + wave * 1024);     \
    async_cp16(vs1 + (size_t)(t) * 128, (char*)KV[buf][1] + 4096 + wave * 1024); \
  } while (0)

  // stage Q + first KV tile
  {
    const char* qsrc0 = qbase + (x0 ^ ((r0 & 7) << 4));
    const char* qsrc1 = qbase + (x1 ^ ((r1 & 7) << 4));
    async_cp16(qsrc0, (char*)QP + wave * 1024);
    async_cp16(qsrc1, (char*)QP + 4096 + wave * 1024);
  }
  STAGE_KV(0, 0);
  __syncthreads();

  // Q fragments (B-operand: col=q=l15, k=d)
  half8 aq[2];
  {
    const int qr = wave * 16 + l15;
#pragma unroll
    for (int hh = 0; hh < 2; ++hh) {
      const int addr = (qr * 128 + hh * 64 + lg * 16) ^ ((qr & 7) << 4);
      aq[hh] = *(const half8*)((const char*)QP + addr);
    }
  }
  char* pw = (char*)QP + wave * 2048;   // wave-private P buffer (= its own Q rows)

  const f32x4 fz = {0.f, 0.f, 0.f, 0.f};
  f32x4 o[4];
#pragma unroll
  for (int i = 0; i < 4; ++i) o[i] = fz;
  float mI = -3.0e38f, lI = 0.f;

  for (int t = 0; t < 32; ++t) {
    const int cb = t & 1;
    if (t < 31) STAGE_KV(cb ^ 1, t + 1);

    // S^T = K * Q : s[n][i] = S[q=l15][kv = n*16 + lg*4 + i]
    f32x4 s[4];
#pragma unroll
    for (int n = 0; n < 4; ++n) s[n] = fz;
#pragma unroll
    for (int n = 0; n < 4; ++n) {
      const int krow = n * 16 + l15;
#pragma unroll
      for (int hh = 0; hh < 2; ++hh) {
        const int addr = (krow * 128 + hh * 64 + lg * 16) ^ ((krow & 7) << 4);
        half8 bk = *(const half8*)((const char*)KV[cb][0] + addr);
        s[n] = __builtin_amdgcn_mfma_f32_16x16x32_f16(bk, aq[hh], s[n], 0, 0, 0);
      }
    }

    // in-lane row max (16 vals) + cross-lg reduce (lanes l15, l15+16, +32, +48)
    float mx = fmaxf(fmaxf(fmaxf(s[0][0], s[0][1]), fmaxf(s[0][2], s[0][3])),
                     fmaxf(fmaxf(s[1][0], s[1][1]), fmaxf(s[1][2], s[1][3])));
    mx = fmaxf(mx, fmaxf(fmaxf(fmaxf(s[2][0], s[2][1]), fmaxf(s[2][2], s[2][3])),
                         fmaxf(fmaxf(s[3][0], s[3][1]), fmaxf(s[3][2], s[3][3]))));
    mx = fmaxf(mx, __shfl_xor(mx, 16));
    mx = fmaxf(mx, __shfl_xor(mx, 32));

    // defer-max (T13): rescale only when some row max grew by > 8 (log2 domain)
    if (!__all(mx <= mI + 8.f)) {
      const float mn = fmaxf(mI, mx);
      const float corr = exp2f(mI - mn);
      mI = mn;
      lI *= corr;
#pragma unroll
      for (int i = 0; i < 4; ++i) {
        const float ci = __shfl(corr, (lane & 48) + lg * 4 + i);
#pragma unroll
        for (int nd = 0; nd < 4; ++nd) o[nd][i] *= ci;
      }
    }

    // p = exp2(s - mI), row-sum
    float p[4][4];
    float rs = 0.f;
#pragma unroll
    for (int n = 0; n < 4; ++n)
#pragma unroll
      for (int i = 0; i < 4; ++i) {
        const float pv = exp2f(s[n][i] - mI);
        p[n][i] = pv; rs += pv;
      }
    rs += __shfl_xor(rs, 16);
    rs += __shfl_xor(rs, 32);
    lI += rs;

    // pack P -> wave-private LDS: row=q (l15), 64 kv * 2B, XOR-swizzled
#pragma unroll
    for (int n = 0; n < 4; ++n) {
      u32 w0 = pack2h(p[n][0], p[n][1]);
      u32 w1 = pack2h(p[n][2], p[n][3]);
      const int addr = (l15 * 128 + n * 32 + lg * 8) ^ ((l15 & 7) << 4);
      uint2 wv; wv.x = w0; wv.y = w1;
      *(uint2*)(pw + addr) = wv;
    }
    half8 pa[2];
#pragma unroll
    for (int hh = 0; hh < 2; ++hh) {
      const int addr = (l15 * 128 + hh * 64 + lg * 16) ^ ((l15 & 7) << 4);
      pa[hh] = *(const half8*)(pw + addr);
    }

    // O += P V  (B-frag from Vt rows: col=d, k=kv)
#pragma unroll
    for (int nd = 0; nd < 4; ++nd) {
      const int dr = nd * 16 + l15;
#pragma unroll
      for (int hh = 0; hh < 2; ++hh) {
        const int addr = (dr * 128 + hh * 64 + lg * 16) ^ ((dr & 7) << 4);
        half8 bv = *(const half8*)((const char*)KV[cb][1] + addr);
        o[nd] = __builtin_amdgcn_mfma_f32_16x16x32_f16(pa[hh], bv, o[nd], 0, 0, 0);
      }
    }
    __syncthreads();
  }
#undef STAGE_KV

  // epilogue: o[nd][i] = O[q=lg*4+i][d=nd*16+l15]; lI lives in lane l15=q
#pragma unroll
  for (int i = 0; i < 4; ++i) {
    const float inv = 1.f / __shfl(lI, (lane & 48) + lg * 4 + i);
    const int t = q0 + wave * 16 + lg * 4 + i;
    u16* orow = O + ((size_t)(b * 2048 + t)) * 1024 + h * 64;
#pragma unroll
    for (int nd = 0; nd < 4; ++nd)
      orow[nd * 16 + l15] = f2h_bits(o[nd][i] * inv);
  }
}

extern "C" void kernel_launch(void* const* d_in, const int* in_sizes, int n_in,
                              void* d_out, int out_size, void* d_ws, size_t ws_size,
                              hipStream_t stream)
{
  const float* q  = (const float*)d_in[0];
  const float* k  = (const float*)d_in[1];
  const float* v  = (const float*)d_in[2];
  const float* Wq = (const float*)d_in[3];
  const float* bq = (const float*)d_in[4];
  const float* Wk = (const float*)d_in[5];
  const float* bk = (const float*)d_in[6];
  const float* Wv = (const float*)d_in[7];
  const float* bv = (const float*)d_in[8];
  const float* Wo = (const float*)d_in[9];
  const float* bo = (const float*)d_in[10];

  u16* W = (u16*)d_ws;
  const unsigned MB = 1u << 20;           // element (u16) units
  u16* wtq = W + 0 * MB;
  u16* wtk = W + 1 * MB;
  u16* wtv = W + 2 * MB;
  u16* wto = W + 3 * MB;
  u16* qhb = W + 4 * MB;                  // 8M elems
  u16* khb = W + 12 * MB;
  u16* vtb = W + 20 * MB;
  u16* Xb  = W + 28 * MB;                 // input cvt buffer / attention output

  transpose_cvt<<<1024, 256, 0, stream>>>(Wq, wtq);
  transpose_cvt<<<1024, 256, 0, stream>>>(Wk, wtk);
  transpose_cvt<<<1024, 256, 0, stream>>>(Wv, wtv);
  transpose_cvt<<<1024, 256, 0, stream>>>(Wo, wto);

  cvt_f16<<<8192, 256, 0, stream>>>((const float4*)q, Xb);
  gemm_kernel<0><<<512, 256, 0, stream>>>(Xb, wtq, bq, qhb);
  cvt_f16<<<8192, 256, 0, stream>>>((const float4*)k, Xb);
  gemm_kernel<1><<<512, 256, 0, stream>>>(Xb, wtk, bk, khb);
  cvt_f16<<<8192, 256, 0, stream>>>((const float4*)v, Xb);
  gemm_kernel<2><<<512, 256, 0, stream>>>(Xb, wtv, bv, vtb);

  attn_kernel<<<2048, 256, 0, stream>>>(qhb, khb, vtb, Xb);
  gemm_kernel<3><<<512, 256, 0, stream>>>(Xb, wto, bo, (float*)d_out);
}